// Round 6
// baseline (233.578 us; speedup 1.0000x reference)
//
#include <hip/hip_runtime.h>
#include <math.h>

#define EPS 1e-8f

// Specialized geometry: frames=64, height=23, width=24 -> tpf=552, hidden=1152,
// interval=1, ntok=35328.
#define TPF   552
#define HID   1152
#define NTOK  35328
#define WID   24

// Pair trick: tasks (f,c) and (f,c+23) share row (f+1,c+24)
// (down-partner of c == right-partner of c+23). One wave handles the pair:
// 5 row loads / 2 tasks (vs 6 naive) = 0.83x cache traffic. All loads
// straight-line; ALL NINE butterfly reductions interleaved in one unrolled
// loop (9-wide ILP, 6 deep) -- R5's sequential reduce64 calls created a
// 54-step serial ds_swizzle chain per wave, which was the regression.
#define PAIRS_PER_FRAME 276          // 12 * 23
#define NPAIRW  17388                // 63 frames * 276
#define NFILLW  20                   // frame-63 fill: 1104 outputs
#define NBLK    4352                 // 4352*4 waves = 17408 = 17388 + 20

struct Row { float4 a, b, c, d; float2 e; };  // 18 floats/lane = 1152/row/wave

__device__ __forceinline__ Row load_row(const float* __restrict__ p, int lane) {
    Row r;
    const float4* p4 = (const float4*)p;
    r.a = p4[lane];       r.b = p4[lane + 64];
    r.c = p4[lane + 128]; r.d = p4[lane + 192];
    r.e = ((const float2*)(p + 1024))[lane];
    return r;
}

__device__ __forceinline__ float dotrr(const Row& x, const Row& y) {
    float s = 0.f;
    s = fmaf(x.a.x, y.a.x, s); s = fmaf(x.a.y, y.a.y, s);
    s = fmaf(x.a.z, y.a.z, s); s = fmaf(x.a.w, y.a.w, s);
    s = fmaf(x.b.x, y.b.x, s); s = fmaf(x.b.y, y.b.y, s);
    s = fmaf(x.b.z, y.b.z, s); s = fmaf(x.b.w, y.b.w, s);
    s = fmaf(x.c.x, y.c.x, s); s = fmaf(x.c.y, y.c.y, s);
    s = fmaf(x.c.z, y.c.z, s); s = fmaf(x.c.w, y.c.w, s);
    s = fmaf(x.d.x, y.d.x, s); s = fmaf(x.d.y, y.d.y, s);
    s = fmaf(x.d.z, y.d.z, s); s = fmaf(x.d.w, y.d.w, s);
    s = fmaf(x.e.x, y.e.x, s); s = fmaf(x.e.y, y.e.y, s);
    return s;
}

__global__ void __launch_bounds__(256) simdiff_pair_kernel(
    const float* __restrict__ x,
    const int* __restrict__ p_frames,
    const int* __restrict__ p_width,
    const int* __restrict__ p_interval,
    float* __restrict__ out)
{
    const int frames   = *p_frames;
    const int width    = *p_width;
    const int interval = *p_interval;
    const int lane     = threadIdx.x & 63;
    const int w        = blockIdx.x * (blockDim.x >> 6) + (threadIdx.x >> 6);

    const bool spec = (frames == 64) && (width == WID) && (interval == 1);

    if (spec) {
        if (w >= NPAIRW) {
            for (int i = (w - NPAIRW) * 64 + lane; i < 2 * TPF; i += NFILLW * 64) {
                if (i < TPF) out[63 * TPF + i]                = -1.f;
                else         out[NTOK + 63 * TPF + (i - TPF)] = -1.f;
            }
            return;
        }
        const int f    = w / PAIRS_PER_FRAME;              // 0..62
        const int p    = w - f * PAIRS_PER_FRAME;          // 0..275
        const int k    = p / 23;                           // 0..11
        const int j    = p - k * 23;                       // 0..22
        const int c1   = 46 * k + j;                       // 0..528
        const int c2   = c1 + 23;                          // 23..551

        const bool dv1 = (c1 < TPF - WID);   // down(c1); right(c1) always valid
        const bool rv2 = (c2 < TPF - 1);     // right(c2)
        const bool dv2 = (c2 < TPF - WID);   // down(c2)

        const float* xf  = x + (size_t)(f * TPF) * HID;
        const float* xf1 = x + (size_t)((f + 1) * TPF) * HID;

        const float* pA1 = xf  + (size_t)c1 * HID;
        const float* pA2 = xf  + (size_t)c2 * HID;
        const float* pB1 = xf1 + (size_t)(c1 + 1) * HID;
        const float* pBs = (dv1 || rv2) ? xf1 + (size_t)(c1 + WID) * HID : pA1;
        const float* pB3 = dv2          ? xf1 + (size_t)(c2 + WID) * HID : pA1;

        // ---- all 5 row loads issued straight-line ----
        const Row A1 = load_row(pA1, lane);
        const Row B1 = load_row(pB1, lane);
        const Row Bs = load_row(pBs, lane);
        const Row A2 = load_row(pA2, lane);
        const Row B3 = load_row(pB3, lane);

        // ---- 9 dot partials (start as rows arrive) ----
        float na1 = dotrr(A1, A1);
        float nb1 = dotrr(B1, B1);
        float d11 = dotrr(A1, B1);   // right(c1)
        float nbs = dotrr(Bs, Bs);
        float d1s = dotrr(A1, Bs);   // down (c1)
        float na2 = dotrr(A2, A2);
        float d2s = dotrr(A2, Bs);   // right(c2)
        float nb3 = dotrr(B3, B3);
        float d23 = dotrr(A2, B3);   // down (c2)

        // ---- ONE interleaved 9-wide butterfly (6 deep) ----
        #pragma unroll
        for (int m = 1; m < 64; m <<= 1) {
            na1 += __shfl_xor(na1, m, 64);
            nb1 += __shfl_xor(nb1, m, 64);
            d11 += __shfl_xor(d11, m, 64);
            nbs += __shfl_xor(nbs, m, 64);
            d1s += __shfl_xor(d1s, m, 64);
            na2 += __shfl_xor(na2, m, 64);
            d2s += __shfl_xor(d2s, m, 64);
            nb3 += __shfl_xor(nb3, m, 64);
            d23 += __shfl_xor(d23, m, 64);
        }

        if (lane == 0) {
            const int t1 = f * TPF + c1;
            const int t2 = f * TPF + c2;
            const float sa1 = fmaxf(sqrtf(na1), EPS);
            const float sa2 = fmaxf(sqrtf(na2), EPS);
            const float sb1 = fmaxf(sqrtf(nb1), EPS);
            const float sbs = fmaxf(sqrtf(nbs), EPS);
            const float sb3 = fmaxf(sqrtf(nb3), EPS);
            out[t1]        = d11 / (sa1 * sb1);
            out[NTOK + t1] = dv1 ? d1s / (sa1 * sbs) : -1.f;
            out[t2]        = rv2 ? d2s / (sa2 * sbs) : -1.f;
            out[NTOK + t2] = dv2 ? d23 / (sa2 * sb3) : -1.f;
        }
        return;
    }

    // ---------- generic fallback (device-param mismatch), grid-stride ----------
    const int ntok    = NTOK;
    const int tpf     = ntok / frames;
    const int valid_f = frames - interval;
    const int stride  = gridDim.x * (blockDim.x >> 6);
    for (int task = w; task < ntok; task += stride) {
        const int f = task / tpf;
        const int i = task - f * tpf;
        const bool rv = (f < valid_f) && (i < tpf - 1);
        const bool dv = (f < valid_f) && (i < tpf - width);
        float out_r = -1.f, out_d = -1.f;
        if (rv || dv) {
            const float* A  = x + (size_t)task * HID;
            const float* B1 = rv ? x + (size_t)((f + interval) * tpf + i + 1) * HID : A;
            const float* B2 = dv ? x + (size_t)((f + interval) * tpf + i + width) * HID : A;
            Row a = load_row(A, lane), b1 = load_row(B1, lane), b2 = load_row(B2, lane);
            float na  = dotrr(a, a);
            float nb1 = dotrr(b1, b1);
            float nb2 = dotrr(b2, b2);
            float d1  = dotrr(a, b1);
            float d2  = dotrr(a, b2);
            #pragma unroll
            for (int m = 1; m < 64; m <<= 1) {
                na  += __shfl_xor(na,  m, 64);
                nb1 += __shfl_xor(nb1, m, 64);
                nb2 += __shfl_xor(nb2, m, 64);
                d1  += __shfl_xor(d1,  m, 64);
                d2  += __shfl_xor(d2,  m, 64);
            }
            const float sa = fmaxf(sqrtf(na), EPS);
            if (rv) out_r = d1 / (sa * fmaxf(sqrtf(nb1), EPS));
            if (dv) out_d = d2 / (sa * fmaxf(sqrtf(nb2), EPS));
        }
        if (lane == 0) {
            out[task]        = out_r;
            out[ntok + task] = out_d;
        }
    }
}

// Fully generic kernel for unexpected host-side sizes.
__global__ void __launch_bounds__(256) simdiff_generic_kernel(
    const float* __restrict__ x,
    const int* __restrict__ p_frames,
    const int* __restrict__ p_width,
    const int* __restrict__ p_interval,
    float* __restrict__ out,
    int ntok, int hidden)
{
    const int frames   = *p_frames;
    const int width    = *p_width;
    const int interval = *p_interval;
    const int tpf      = ntok / frames;
    const int valid_f  = frames - interval;
    const int lane     = threadIdx.x & 63;
    const int stride   = gridDim.x * (blockDim.x >> 6);
    const int nvec     = hidden >> 2;

    for (int task = blockIdx.x * (blockDim.x >> 6) + (threadIdx.x >> 6);
         task < ntok; task += stride) {
        const int f = task / tpf;
        const int i = task - f * tpf;
        const bool rv = (f < valid_f) && (i < tpf - 1);
        const bool dv = (f < valid_f) && (i < tpf - width);
        float out_r = -1.f, out_d = -1.f;
        if (rv || dv) {
            const float4* A  = (const float4*)(x + (size_t)task * hidden);
            const float4* B1 = rv ? (const float4*)(x + (size_t)((f + interval) * tpf + i + 1) * hidden) : A;
            const float4* B2 = dv ? (const float4*)(x + (size_t)((f + interval) * tpf + i + width) * hidden) : A;
            float na2 = 0.f, nb1 = 0.f, nb2 = 0.f, d1 = 0.f, d2 = 0.f;
            for (int v = lane; v < nvec; v += 64) {
                const float4 a = A[v];
                na2 = fmaf(a.x,a.x, fmaf(a.y,a.y, fmaf(a.z,a.z, fmaf(a.w,a.w, na2))));
                const float4 b = B1[v];
                nb1 = fmaf(b.x,b.x, fmaf(b.y,b.y, fmaf(b.z,b.z, fmaf(b.w,b.w, nb1))));
                d1  = fmaf(a.x,b.x, fmaf(a.y,b.y, fmaf(a.z,b.z, fmaf(a.w,b.w, d1))));
                const float4 cc = B2[v];
                nb2 = fmaf(cc.x,cc.x, fmaf(cc.y,cc.y, fmaf(cc.z,cc.z, fmaf(cc.w,cc.w, nb2))));
                d2  = fmaf(a.x,cc.x, fmaf(a.y,cc.y, fmaf(a.z,cc.z, fmaf(a.w,cc.w, d2))));
            }
            #pragma unroll
            for (int m = 1; m < 64; m <<= 1) {
                na2 += __shfl_xor(na2, m, 64);
                nb1 += __shfl_xor(nb1, m, 64);
                nb2 += __shfl_xor(nb2, m, 64);
                d1  += __shfl_xor(d1, m, 64);
                d2  += __shfl_xor(d2, m, 64);
            }
            const float sa = fmaxf(sqrtf(na2), EPS);
            if (rv) out_r = d1 / (sa * fmaxf(sqrtf(nb1), EPS));
            if (dv) out_d = d2 / (sa * fmaxf(sqrtf(nb2), EPS));
        }
        if (lane == 0) {
            out[task]        = out_r;
            out[ntok + task] = out_d;
        }
    }
}

extern "C" void kernel_launch(void* const* d_in, const int* in_sizes, int n_in,
                              void* d_out, int out_size, void* d_ws, size_t ws_size,
                              hipStream_t stream) {
    const float* x        = (const float*)d_in[0];
    const int* p_frames   = (const int*)d_in[1];
    const int* p_width    = (const int*)d_in[3];
    const int* p_interval = (const int*)d_in[4];
    float* out            = (float*)d_out;

    const int ntok   = out_size / 2;
    const int hidden = in_sizes[0] / ntok;

    if (ntok == NTOK && hidden == HID) {
        simdiff_pair_kernel<<<NBLK, 256, 0, stream>>>(
            x, p_frames, p_width, p_interval, out);
    } else {
        const int blocks = (ntok + 3) / 4;
        simdiff_generic_kernel<<<blocks, 256, 0, stream>>>(
            x, p_frames, p_width, p_interval, out, ntok, hidden);
    }
}

// Round 7
// 224.559 us; speedup vs baseline: 1.0402x; 1.0402x over previous
//
#include <hip/hip_runtime.h>
#include <math.h>

#define EPS 1e-8f

// FINAL (R2 structure, best measured 224.8 us total; kernel ~39 us).
// One wave per token. hidden==1152 specialization: 4x float4 + 1x float2 per
// lane per row; all 15 loads (3 rows x 5) issued straight-line up front so
// memory latency overlaps; 5 butterfly reductions interleaved (5-wide ILP).
//
// Why no fancier structure: the input (163 MB) is L3-resident when the kernel
// runs (harness restores it via D2D copy each iteration). The kernel serves
// 490 MB of logical reads at ~12.6 TB/s = the L3/fabric service ceiling.
// At that ceiling the binding resource is concurrent outstanding requests:
// 35328 independent waves x 15 loads wins. Measured alternatives all lost:
//   R3 XCD-chunk swizzle        +7.7 us (dispatcher placement model wrong)
//   R4 chain-12 (0.69x traffic) +11 us  (serial 12-step loop, 2.8 waves/SIMD)
//   R5/R6 pair   (0.83x traffic) +8 us  (90 payload VGPRs -> occupancy drop)
__global__ void __launch_bounds__(256) simdiff_1152_kernel(
    const float* __restrict__ x,
    const int* __restrict__ p_frames,
    const int* __restrict__ p_width,
    const int* __restrict__ p_interval,
    float* __restrict__ out,
    int ntok)
{
    const int frames   = *p_frames;
    const int width    = *p_width;
    const int interval = *p_interval;
    const int tpf      = ntok / frames;
    const int valid_f  = frames - interval;

    const int lane = threadIdx.x & 63;
    const int task = blockIdx.x * (blockDim.x >> 6) + (threadIdx.x >> 6);
    if (task >= ntok) return;

    const int f = task / tpf;
    const int i = task - f * tpf;

    const bool rv = (f < valid_f) && (i < tpf - 1);      // right valid
    const bool dv = (f < valid_f) && (i < tpf - width);  // down  valid

    float out_r = -1.0f, out_d = -1.0f;

    if (rv || dv) {
        const float* A  = x + (size_t)task * 1152;
        const float* B1 = rv ? x + (size_t)((f + interval) * tpf + i + 1) * 1152     : A;
        const float* B2 = dv ? x + (size_t)((f + interval) * tpf + i + width) * 1152 : A;

        const float4* A4  = (const float4*)A;
        const float4* B14 = (const float4*)B1;
        const float4* B24 = (const float4*)B2;
        const float2* A2  = (const float2*)(A  + 1024);
        const float2* B12 = (const float2*)(B1 + 1024);
        const float2* B22 = (const float2*)(B2 + 1024);

        // ---- issue all 15 independent loads ----
        const float4 a0 = A4[lane];       const float4 a1 = A4[lane + 64];
        const float4 a2 = A4[lane + 128]; const float4 a3 = A4[lane + 192];
        const float2 a4 = A2[lane];

        const float4 p0 = B14[lane];       const float4 p1 = B14[lane + 64];
        const float4 p2 = B14[lane + 128]; const float4 p3 = B14[lane + 192];
        const float2 p4 = B12[lane];

        const float4 q0 = B24[lane];       const float4 q1 = B24[lane + 64];
        const float4 q2 = B24[lane + 128]; const float4 q3 = B24[lane + 192];
        const float2 q4 = B22[lane];

        float na2 = 0.f, nb1 = 0.f, nb2 = 0.f, d1 = 0.f, d2 = 0.f;

        #define ACC4(v)  na2 = fmaf(v.x,v.x, fmaf(v.y,v.y, fmaf(v.z,v.z, fmaf(v.w,v.w, na2))))
        #define NB14(v)  nb1 = fmaf(v.x,v.x, fmaf(v.y,v.y, fmaf(v.z,v.z, fmaf(v.w,v.w, nb1))))
        #define NB24(v)  nb2 = fmaf(v.x,v.x, fmaf(v.y,v.y, fmaf(v.z,v.z, fmaf(v.w,v.w, nb2))))
        #define DOT14(a,b) d1 = fmaf(a.x,b.x, fmaf(a.y,b.y, fmaf(a.z,b.z, fmaf(a.w,b.w, d1))))
        #define DOT24(a,b) d2 = fmaf(a.x,b.x, fmaf(a.y,b.y, fmaf(a.z,b.z, fmaf(a.w,b.w, d2))))

        ACC4(a0); ACC4(a1); ACC4(a2); ACC4(a3);
        na2 = fmaf(a4.x, a4.x, fmaf(a4.y, a4.y, na2));

        NB14(p0); NB14(p1); NB14(p2); NB14(p3);
        nb1 = fmaf(p4.x, p4.x, fmaf(p4.y, p4.y, nb1));
        DOT14(a0, p0); DOT14(a1, p1); DOT14(a2, p2); DOT14(a3, p3);
        d1 = fmaf(a4.x, p4.x, fmaf(a4.y, p4.y, d1));

        NB24(q0); NB24(q1); NB24(q2); NB24(q3);
        nb2 = fmaf(q4.x, q4.x, fmaf(q4.y, q4.y, nb2));
        DOT24(a0, q0); DOT24(a1, q1); DOT24(a2, q2); DOT24(a3, q3);
        d2 = fmaf(a4.x, q4.x, fmaf(a4.y, q4.y, d2));

        // ---- interleaved 5-wide butterfly (6 deep) ----
        #pragma unroll
        for (int m = 1; m < 64; m <<= 1) {
            na2 += __shfl_xor(na2, m, 64);
            nb1 += __shfl_xor(nb1, m, 64);
            nb2 += __shfl_xor(nb2, m, 64);
            d1  += __shfl_xor(d1, m, 64);
            d2  += __shfl_xor(d2, m, 64);
        }

        const float na = fmaxf(sqrtf(na2), EPS);
        if (rv) out_r = d1 / (na * fmaxf(sqrtf(nb1), EPS));
        if (dv) out_d = d2 / (na * fmaxf(sqrtf(nb2), EPS));
    }

    if (lane == 0) {
        out[task]        = out_r;
        out[ntok + task] = out_d;
    }
}

// Generic fallback (any hidden).
__global__ void __launch_bounds__(256) simdiff_generic_kernel(
    const float* __restrict__ x,
    const int* __restrict__ p_frames,
    const int* __restrict__ p_width,
    const int* __restrict__ p_interval,
    float* __restrict__ out,
    int ntok, int hidden)
{
    const int frames   = *p_frames;
    const int width    = *p_width;
    const int interval = *p_interval;
    const int tpf      = ntok / frames;
    const int valid_f  = frames - interval;

    const int lane            = threadIdx.x & 63;
    const int wave_in_block   = threadIdx.x >> 6;
    const int waves_per_block = blockDim.x >> 6;
    const int stride          = gridDim.x * waves_per_block;
    const int nvec            = hidden >> 2;

    for (int task = blockIdx.x * waves_per_block + wave_in_block;
         task < ntok; task += stride) {
        const int f = task / tpf;
        const int i = task - f * tpf;
        const bool rv = (f < valid_f) && (i < tpf - 1);
        const bool dv = (f < valid_f) && (i < tpf - width);
        float out_r = -1.0f, out_d = -1.0f;

        if (rv || dv) {
            const float4* A  = (const float4*)(x + (size_t)task * hidden);
            const float4* B1 = rv ? (const float4*)(x + (size_t)((f + interval) * tpf + i + 1) * hidden) : A;
            const float4* B2 = dv ? (const float4*)(x + (size_t)((f + interval) * tpf + i + width) * hidden) : A;
            float na2 = 0.f, nb1 = 0.f, nb2 = 0.f, d1 = 0.f, d2 = 0.f;
            for (int v = lane; v < nvec; v += 64) {
                const float4 a = A[v];
                na2 = fmaf(a.x,a.x, fmaf(a.y,a.y, fmaf(a.z,a.z, fmaf(a.w,a.w, na2))));
                const float4 bb = B1[v];
                nb1 = fmaf(bb.x,bb.x, fmaf(bb.y,bb.y, fmaf(bb.z,bb.z, fmaf(bb.w,bb.w, nb1))));
                d1  = fmaf(a.x,bb.x, fmaf(a.y,bb.y, fmaf(a.z,bb.z, fmaf(a.w,bb.w, d1))));
                const float4 c = B2[v];
                nb2 = fmaf(c.x,c.x, fmaf(c.y,c.y, fmaf(c.z,c.z, fmaf(c.w,c.w, nb2))));
                d2  = fmaf(a.x,c.x, fmaf(a.y,c.y, fmaf(a.z,c.z, fmaf(a.w,c.w, d2))));
            }
            #pragma unroll
            for (int m = 1; m < 64; m <<= 1) {
                na2 += __shfl_xor(na2, m, 64);
                nb1 += __shfl_xor(nb1, m, 64);
                nb2 += __shfl_xor(nb2, m, 64);
                d1  += __shfl_xor(d1, m, 64);
                d2  += __shfl_xor(d2, m, 64);
            }
            const float na = fmaxf(sqrtf(na2), EPS);
            if (rv) out_r = d1 / (na * fmaxf(sqrtf(nb1), EPS));
            if (dv) out_d = d2 / (na * fmaxf(sqrtf(nb2), EPS));
        }
        if (lane == 0) {
            out[task]        = out_r;
            out[ntok + task] = out_d;
        }
    }
}

extern "C" void kernel_launch(void* const* d_in, const int* in_sizes, int n_in,
                              void* d_out, int out_size, void* d_ws, size_t ws_size,
                              hipStream_t stream) {
    const float* x        = (const float*)d_in[0];
    const int* p_frames   = (const int*)d_in[1];
    const int* p_width    = (const int*)d_in[3];
    const int* p_interval = (const int*)d_in[4];
    float* out            = (float*)d_out;

    const int ntok   = out_size / 2;
    const int hidden = in_sizes[0] / ntok;

    const int threads         = 256;
    const int waves_per_block = threads / 64;
    const int blocks          = (ntok + waves_per_block - 1) / waves_per_block;

    if (hidden == 1152) {
        simdiff_1152_kernel<<<blocks, threads, 0, stream>>>(
            x, p_frames, p_width, p_interval, out, ntok);
    } else {
        simdiff_generic_kernel<<<blocks, threads, 0, stream>>>(
            x, p_frames, p_width, p_interval, out, ntok, hidden);
    }
}